// Round 5
// baseline (574.579 us; speedup 1.0000x reference)
//
#include <hip/hip_runtime.h>
#include <cmath>

// AttentionBlock fused pipeline for MI355X (gfx950). Dtype-adaptive:
// probe detects fp32 vs bf16 input; compute runs in bf16 MFMA; epilogue
// honors the real dtype.
//
// B=4, C=256, N=32768, G=4 (64ch/group), NH=8, hd=32.
//
// This revision: multi-tile persistent GEMM blocks. Each block processes
// several 128x128 output tiles back-to-back; the double-buffered 2-phase
// K-loop stays warm ACROSS tile boundaries (stage of tile t+1's first
// K-step is issued during tile t's last K-step). Epilogue uses the just-
// consumed LDS region (parity => always region 1) while the next tile's
// data sits in region 0. gemm2: 4 tiles/block, grid 512 = 2 blocks/CU
// resident, no queue tail. gemm1: 2 tiles/block, grid 512*nb.
// k_sim: 256-thread blocks (4 chunks/block) for 4x wave occupancy.

typedef __bf16 bf16x8 __attribute__((ext_vector_type(8)));
typedef float f32x4 __attribute__((ext_vector_type(4)));

union U16 { uint4 u; unsigned short s[8]; bf16x8 v; };

__device__ __forceinline__ float bf2f(unsigned short h) {
    unsigned int u = ((unsigned int)h) << 16;
    return __builtin_bit_cast(float, u);
}
__device__ __forceinline__ unsigned short f2bf(float f) {
    unsigned int u = __builtin_bit_cast(unsigned int, f);
    u = (u + 0x7fffu + ((u >> 16) & 1u)) >> 16;   // RNE
    return (unsigned short)u;
}
__device__ __forceinline__ unsigned int pack2(unsigned short a, unsigned short b) {
    return (unsigned int)a | ((unsigned int)b << 16);
}

// ------------------------------------------------------------- dtype probe
__global__ __launch_bounds__(64) void k_detect(const unsigned int* __restrict__ xr,
                                               int* __restrict__ flag) {
    unsigned int u = xr[threadIdx.x * 997];
    int e = (u >> 7) & 0xFF;
    bool ok = (e >= 100) && (e <= 141);
    unsigned long long m = __ballot(ok);
    if (threadIdx.x == 0) *flag = (__popcll(m) < 32) ? 1 : 0;   // 1 = fp32
}

// --------------------------------------------------- weight convert / copy
// wdst: qkvw[196608] | outw[65536] | gnw[256] | gnb[256] | outb[256] | wqT[65536]
__global__ __launch_bounds__(256) void k_cvt_w(const void* __restrict__ qkvw,
                                               const void* __restrict__ outw,
                                               const void* __restrict__ gnw,
                                               const void* __restrict__ gnb,
                                               const void* __restrict__ outb,
                                               const int* __restrict__ flagp,
                                               unsigned short* __restrict__ wdst) {
    int idx = blockIdx.x * 256 + threadIdx.x;
    if (idx >= 328448) return;
    int f = *flagp;
    const void* src; int off;
    if      (idx < 196608) { src = qkvw; off = idx; }
    else if (idx < 262144) { src = outw; off = idx - 196608; }
    else if (idx < 262400) { src = gnw;  off = idx - 262144; }
    else if (idx < 262656) { src = gnb;  off = idx - 262400; }
    else if (idx < 262912) { src = outb; off = idx - 262656; }
    else {  // wqT[c][d] = qkvw[d][c], q-part only (d<256)
        int i = idx - 262912;
        int c = i >> 8, d = i & 255;
        src = qkvw; off = d * 256 + c;
    }
    wdst[idx] = f ? f2bf(((const float*)src)[off])
                  : ((const unsigned short*)src)[off];
}

// ---------------------------------------------------------------- GN stats
__global__ __launch_bounds__(256) void k_gnsum(const void* __restrict__ xr,
                                               const int* __restrict__ flagp,
                                               float2* __restrict__ gn_part) {
    int t = threadIdx.x, bid = blockIdx.x;
    int grp = bid >> 7, chunk = bid & 127;
    size_t base = (size_t)grp * 2097152 + (size_t)chunk * 16384;
    int f = *flagp;
    float s = 0.f, q = 0.f;
    if (f) {
        const float* p = (const float*)xr + base;
        for (int i = 0; i < 8; i++) {
            float4 a = *(const float4*)(p + i * 2048 + t * 8);
            float4 b = *(const float4*)(p + i * 2048 + t * 8 + 4);
            float v[8] = {a.x, a.y, a.z, a.w, b.x, b.y, b.z, b.w};
#pragma unroll
            for (int j = 0; j < 8; j++) { s += v[j]; q += v[j] * v[j]; }
        }
    } else {
        const unsigned short* p = (const unsigned short*)xr + base;
        for (int i = 0; i < 8; i++) {
            U16 u; u.u = *(const uint4*)(p + i * 2048 + t * 8);
#pragma unroll
            for (int j = 0; j < 8; j++) { float v = bf2f(u.s[j]); s += v; q += v * v; }
        }
    }
#pragma unroll
    for (int off = 32; off > 0; off >>= 1) { s += __shfl_xor(s, off); q += __shfl_xor(q, off); }
    __shared__ float rs[4], rq[4];
    int wave = t >> 6;
    if ((t & 63) == 0) { rs[wave] = s; rq[wave] = q; }
    __syncthreads();
    if (t == 0) gn_part[bid] = make_float2(rs[0] + rs[1] + rs[2] + rs[3],
                                           rq[0] + rq[1] + rq[2] + rq[3]);
}

__global__ __launch_bounds__(128) void k_gnfinal(const float2* __restrict__ gn_part,
                                                 float2* __restrict__ gstats) {
    int bg = blockIdx.x, t = threadIdx.x;
    float2 v = gn_part[bg * 128 + t];
    float s = v.x, q = v.y;
#pragma unroll
    for (int off = 32; off > 0; off >>= 1) { s += __shfl_xor(s, off); q += __shfl_xor(q, off); }
    __shared__ float rs[2], rq[2];
    if ((t & 63) == 0) { rs[t >> 6] = s; rq[t >> 6] = q; }
    __syncthreads();
    if (t == 0) {
        const float inv = 1.0f / 2097152.0f;
        float S = rs[0] + rs[1], Q = rq[0] + rq[1];
        float mean = S * inv;
        float var = Q * inv - mean * mean;
        gstats[bg] = make_float2(mean, rsqrtf(var + 1e-5f));
    }
}

// ---------------------------------------------------------------- beta_b[o]
__global__ __launch_bounds__(64) void k_beta(const unsigned short* __restrict__ wq,
                                             const unsigned short* __restrict__ wgnw,
                                             const unsigned short* __restrict__ wgnb,
                                             const float2* __restrict__ gstats,
                                             float* __restrict__ beta) {
    int bid = blockIdx.x;
    int b = bid / 768, o = bid % 768;
    int t = threadIdx.x, c = t * 4;
    float2 ms = gstats[b * 4 + (c >> 6)];
    uint2 qw = *(const uint2*)(wq + o * 256 + c);
    uint2 gw = *(const uint2*)(wgnw + c);
    uint2 gb = *(const uint2*)(wgnb + c);
    unsigned short qs[4] = {(unsigned short)(qw.x & 0xffff), (unsigned short)(qw.x >> 16),
                            (unsigned short)(qw.y & 0xffff), (unsigned short)(qw.y >> 16)};
    unsigned short wsx[4] = {(unsigned short)(gw.x & 0xffff), (unsigned short)(gw.x >> 16),
                             (unsigned short)(gw.y & 0xffff), (unsigned short)(gw.y >> 16)};
    unsigned short bs[4] = {(unsigned short)(gb.x & 0xffff), (unsigned short)(gb.x >> 16),
                            (unsigned short)(gb.y & 0xffff), (unsigned short)(gb.y >> 16)};
    float bacc = 0.f;
#pragma unroll
    for (int j = 0; j < 4; j++)
        bacc += bf2f(qs[j]) * (bf2f(bs[j]) - ms.x * ms.y * bf2f(wsx[j]));
#pragma unroll
    for (int off = 32; off > 0; off >>= 1) bacc += __shfl_xor(bacc, off);
    if (t == 0) beta[b * 768 + o] = bacc;
}

// --------------------------- convert + transpose + fold GN scale (raw x -> xt)
__global__ __launch_bounds__(256) void k_cvt_t(const void* __restrict__ xr,
                                               const int* __restrict__ flagp,
                                               const unsigned short* __restrict__ wgnw,
                                               const float2* __restrict__ gstats,
                                               unsigned short* __restrict__ xt) {
    int tid = threadIdx.x, bid = blockIdx.x;
    int b = bid >> 11, r2 = bid & 2047, cblk = r2 >> 9, nblk = r2 & 511;
    float rstd = gstats[b * 4 + cblk].y;
    int f = *flagp;
    __shared__ __align__(16) unsigned short T[64 * 80];
    unsigned short tmp[2][8];
#pragma unroll
    for (int i = 0; i < 2; i++) {
        int crow = (tid >> 3) + 32 * i, nch = tid & 7;
        int c = cblk * 64 + crow;
        float sc = bf2f(wgnw[c]) * rstd;
        size_t base = ((size_t)(b * 256 + c)) * 32768 + (size_t)nblk * 64 + nch * 8;
        float v[8];
        if (f) {
            float4 a = *(const float4*)((const float*)xr + base);
            float4 d = *(const float4*)((const float*)xr + base + 4);
            v[0] = a.x; v[1] = a.y; v[2] = a.z; v[3] = a.w;
            v[4] = d.x; v[5] = d.y; v[6] = d.z; v[7] = d.w;
        } else {
            U16 u; u.u = *(const uint4*)((const unsigned short*)xr + base);
#pragma unroll
            for (int j = 0; j < 8; j++) v[j] = bf2f(u.s[j]);
        }
#pragma unroll
        for (int j = 0; j < 8; j++) tmp[i][j] = f2bf(v[j] * sc);
    }
#pragma unroll
    for (int i = 0; i < 2; i++) {
        int crow = (tid >> 3) + 32 * i, nch = tid & 7;
#pragma unroll
        for (int jj = 0; jj < 8; jj++) {
            int j = (jj + tid) & 7;
            T[(nch * 8 + j) * 80 + crow] = tmp[i][j];
        }
    }
    __syncthreads();
#pragma unroll
    for (int i = 0; i < 2; i++) {
        int nrow = (tid >> 3) + 32 * i, cch = tid & 7;
        uint4 v = *(const uint4*)&T[nrow * 80 + cch * 8];
        *(uint4*)(xt + ((size_t)b * 32768 + (size_t)nblk * 64 + nrow) * 256 + cblk * 64 + cch * 8) = v;
    }
}

// ---------------------------------------------------------------- GEMM core
// LDS tile [row][64 bf16], LINEAR layout fed by global_load_lds; the XOR
// chunk swizzle (logical chunk c of row r lives at slot c^(r&7)) is applied
// on the per-lane GLOBAL source address; ds_read applies the same XOR.
__device__ __forceinline__ void stage_tile(const unsigned short* __restrict__ g, int stride,
                                           unsigned short* __restrict__ lds, int tid) {
    int lane = tid & 63, wave = tid >> 6;
    int r8 = lane >> 3, s = lane & 7;
#pragma unroll
    for (int i = 0; i < 4; i++) {
        int row0 = wave * 32 + i * 8;
        int row = row0 + r8;
        const unsigned short* src = g + (size_t)row * stride + ((s ^ (row & 7)) << 3);
        // lane l of the wave writes lds_base + l*16 (HW-linear); src is per-lane.
        __builtin_amdgcn_global_load_lds(
            (__attribute__((address_space(1))) void*)src,
            (__attribute__((address_space(3))) void*)(lds + row0 * 64),
            16, 0, 0);
    }
}

__device__ __forceinline__ void mfma_tile(const unsigned short* __restrict__ ldsA,
                                          const unsigned short* __restrict__ ldsB,
                                          int l15, int quad, int wm, int wn,
                                          f32x4 (&acc)[4][4]) {
#pragma unroll
    for (int ks = 0; ks < 2; ks++) {
        bf16x8 af[4], bv[4];
#pragma unroll
        for (int mi = 0; mi < 4; mi++) {
            int row = wm * 64 + mi * 16 + l15;
            af[mi] = *(const bf16x8*)&ldsA[row * 64 + (((ks * 4 + quad) ^ (row & 7)) * 8)];
        }
#pragma unroll
        for (int ni = 0; ni < 4; ni++) {
            int row = wn * 64 + ni * 16 + l15;
            bv[ni] = *(const bf16x8*)&ldsB[row * 64 + (((ks * 4 + quad) ^ (row & 7)) * 8)];
        }
#pragma unroll
        for (int mi = 0; mi < 4; mi++)
#pragma unroll
            for (int ni = 0; ni < 4; ni++)
                acc[mi][ni] = __builtin_amdgcn_mfma_f32_16x16x32_bf16(af[mi], bv[ni], acc[mi][ni], 0, 0, 0);
    }
}

// Double-buffered pipelined K-loop (single-tile form, used by buildG).
template<int KSTEPS, int KAMASK>
__device__ __forceinline__ void gemm_core_db(const unsigned short* __restrict__ A, int strideA,
                                             const unsigned short* __restrict__ B, int strideB,
                                             unsigned short* lds, int tid, f32x4 (&acc)[4][4]) {
    int lane = tid & 63, l15 = lane & 15, quad = lane >> 4;
    int wave = tid >> 6, wm = wave & 1, wn = wave >> 1;
    stage_tile(A, strideA, lds, tid);
    stage_tile(B, strideB, lds + 8192, tid);
    __syncthreads();
#pragma unroll
    for (int kt = 0; kt < KSTEPS; ++kt) {
        unsigned short* cur = lds + (kt & 1) * 16384;
        unsigned short* nxt = lds + (((kt & 1) ^ 1)) * 16384;
        if (kt + 1 < KSTEPS) {
            stage_tile(A + ((kt + 1) & KAMASK) * 64, strideA, nxt, tid);
            stage_tile(B + (kt + 1) * 64, strideB, nxt + 8192, tid);
        }
        mfma_tile(cur, cur + 8192, l15, quad, wm, wn, acc);
        __syncthreads();
    }
}

// GEMM1: kv = wq_kv . xt^T + beta. Multi-tile persistent: 2 n-tiles/block,
// pipeline warm across tiles. Grid 512*nb (2 blocks/CU resident at nb=1).
__global__ __launch_bounds__(256) void k_gemm1(const unsigned short* __restrict__ wq,
                                               const unsigned short* __restrict__ xt,
                                               const float* __restrict__ beta,
                                               unsigned short* __restrict__ kv,
                                               int b0) {
    __shared__ __align__(16) unsigned short lds[4 * 8192];   // 64 KB
    int tid = threadIdx.x, bid = blockIdx.x;
    // XCD-grouped bijective swizzle (grid % 8 == 0).
    int cpx = (int)gridDim.x >> 3;
    int L = (bid & 7) * cpx + (bid >> 3);
    int mblk = L & 3;                    // 4 mblks sharing xt adjacent on XCD
    int ngrp = (L >> 2) & 127;           // 128 groups of 2 n-tiles
    int bl = L >> 9;
    int gb = b0 + bl;
    int o0 = 256 + mblk * 128;           // qkv row index (k/v region)
    const unsigned short* A = wq + (size_t)o0 * 256;
    const unsigned short* Bb = xt + ((size_t)gb * 32768 + (size_t)ngrp * 256) * 256;
    int lane = tid & 63, l15 = lane & 15, quad = lane >> 4;
    int wave = tid >> 6, wm = wave & 1, wn = wave >> 1;
    int kv0 = mblk * 128;

    stage_tile(A, 256, lds, tid);
    stage_tile(Bb, 256, lds + 8192, tid);
    __syncthreads();
    for (int t = 0; t < 2; ++t) {
        f32x4 acc[4][4] = {};
#pragma unroll
        for (int kt = 0; kt < 4; ++kt) {
            int g = t * 4 + kt;
            unsigned short* cur = lds + (g & 1) * 16384;
            unsigned short* nxt = lds + ((g + 1) & 1) * 16384;
            if (g + 1 < 8) {
                int g2 = g + 1, t2 = g2 >> 2, k2 = g2 & 3;
                stage_tile(A + k2 * 64, 256, nxt, tid);
                stage_tile(Bb + ((size_t)t2 * 128) * 256 + k2 * 64, 256, nxt + 8192, tid);
            }
            mfma_tile(cur, cur + 8192, l15, quad, wm, wn, acc);
            __syncthreads();
        }
        // Epilogue tile t: scratch = region 1 (last g of tile is odd); the
        // next tile's first K-step data sits untouched in region 0.
        unsigned short* scr = lds + 16384;
        size_t n0 = ((size_t)ngrp * 2 + t) * 128;
#pragma unroll
        for (int mi = 0; mi < 4; mi++) {
            int o_l = wm * 64 + mi * 16 + quad * 4;
            float4 be = *(const float4*)(beta + gb * 768 + o0 + o_l);
            float bev[4] = {be.x, be.y, be.z, be.w};
#pragma unroll
            for (int ni = 0; ni < 4; ni++) {
                int n_l = wn * 64 + ni * 16 + l15;
                f32x4 v = acc[mi][ni];
#pragma unroll
                for (int r = 0; r < 4; r++) {
                    int o_r = o_l + r;
                    scr[(o_r * 128 + n_l) ^ ((o_r & 7) << 3)] = f2bf(v[r] + bev[r]);
                }
            }
        }
        __syncthreads();
#pragma unroll
        for (int p = 0; p < 8; p++) {
            int o_r = p * 16 + (tid >> 4);
            int ch = tid & 15;
            uint4 v = *(const uint4*)&scr[(o_r * 128 + ch * 8) ^ ((o_r & 7) << 3)];
            *(uint4*)(kv + ((size_t)bl * 512 + kv0 + o_r) * 32768 + n0 + ch * 8) = v;
        }
        __syncthreads();   // protect scratch before next stage targets region 1
    }
}

// ------------------------------------------------- softmax row stats (pass-local)
__global__ __launch_bounds__(256) void k_stats(const unsigned short* __restrict__ kv,
                                               float2* __restrict__ stats) {
    int row = blockIdx.x, t = threadIdx.x;
    const unsigned short* p = kv + ((size_t)(row >> 8) * 512 + (row & 255)) * 32768;
    float m = -3.0e38f;
    for (int i = 0; i < 16; i++) {
        U16 u; u.u = *(const uint4*)(p + i * 2048 + t * 8);
#pragma unroll
        for (int j = 0; j < 8; j++) m = fmaxf(m, bf2f(u.s[j]));
    }
#pragma unroll
    for (int off = 32; off > 0; off >>= 1) m = fmaxf(m, __shfl_xor(m, off));
    __shared__ float rm[4], rs[4];
    int wave = t >> 6;
    if ((t & 63) == 0) rm[wave] = m;
    __syncthreads();
    m = fmaxf(fmaxf(rm[0], rm[1]), fmaxf(rm[2], rm[3]));
    float s = 0.f;
    for (int i = 0; i < 16; i++) {
        U16 u; u.u = *(const uint4*)(p + i * 2048 + t * 8);
#pragma unroll
        for (int j = 0; j < 8; j++) s += __expf(bf2f(u.s[j]) - m);
    }
#pragma unroll
    for (int off = 32; off > 0; off >>= 1) s += __shfl_xor(s, off);
    if ((t & 63) == 0) rs[wave] = s;
    __syncthreads();
    if (t == 0) stats[row] = make_float2(m, 1.0f / (rs[0] + rs[1] + rs[2] + rs[3]));
}

// ----------------------------- sim partials (pass-local), 4 waves = 4 chunks/block
__global__ __launch_bounds__(256) void k_sim(const unsigned short* __restrict__ kv,
                                             const float2* __restrict__ stats,
                                             float* __restrict__ partials) {
    int bid = blockIdx.x;
    int bh = bid >> 4;
    int chunk = (bid & 15) * 4 + (threadIdx.x >> 6);
    int b = bh >> 3, h = bh & 7;
    int lane = threadIdx.x & 63, l15 = lane & 15, quad = lane >> 4;
    size_t n0 = (size_t)chunk * 512 + quad * 8;
    float mrow[2], isr[2];
#pragma unroll
    for (int mi = 0; mi < 2; mi++) {
        float2 st = stats[b * 256 + h * 32 + mi * 16 + l15];
        mrow[mi] = st.x; isr[mi] = st.y;
    }
    const unsigned short* kb = kv + ((size_t)b * 512 + h * 32) * 32768;
    const unsigned short* vb = kv + ((size_t)b * 512 + 256 + h * 32) * 32768;
    f32x4 acc[2][2] = {};
    for (int t = 0; t < 16; t++) {
        size_t n = n0 + t * 32;
        bf16x8 af[2], bv[2];
#pragma unroll
        for (int mi = 0; mi < 2; mi++) {
            U16 u; u.u = *(const uint4*)(kb + (size_t)(mi * 16 + l15) * 32768 + n);
            U16 pv;
#pragma unroll
            for (int j = 0; j < 8; j++) pv.s[j] = f2bf(__expf(bf2f(u.s[j]) - mrow[mi]) * isr[mi]);
            af[mi] = pv.v;
        }
#pragma unroll
        for (int ni = 0; ni < 2; ni++) {
            U16 u; u.u = *(const uint4*)(vb + (size_t)(ni * 16 + l15) * 32768 + n);
            bv[ni] = u.v;
        }
#pragma unroll
        for (int mi = 0; mi < 2; mi++)
#pragma unroll
            for (int ni = 0; ni < 2; ni++)
                acc[mi][ni] = __builtin_amdgcn_mfma_f32_16x16x32_bf16(af[mi], bv[ni], acc[mi][ni], 0, 0, 0);
    }
    float* po = partials + (size_t)(bh * 64 + chunk) * 1024;
#pragma unroll
    for (int mi = 0; mi < 2; mi++)
#pragma unroll
        for (int ni = 0; ni < 2; ni++)
#pragma unroll
            for (int rr = 0; rr < 4; rr++)
                po[(mi * 16 + quad * 4 + rr) * 32 + ni * 16 + l15] = acc[mi][ni][rr];
}

__global__ __launch_bounds__(256) void k_combine(const float* __restrict__ partials,
                                                 float* __restrict__ sim, int b0) {
    int bh = blockIdx.x, tid = threadIdx.x;
#pragma unroll
    for (int i = 0; i < 4; i++) {
        float a = 0.f;
        const float* p = partials + (size_t)bh * 65536 + tid + i * 256;
        for (int c = 0; c < 64; c++) a += p[(size_t)c * 1024];
        sim[(size_t)(b0 * 8 + bh) * 1024 + tid + i * 256] = a;
    }
}

// buildM + folded gamma: M[b][o][c] and gamma[b][o] = M.beta_q + out_b
__global__ __launch_bounds__(256) void k_buildM(const unsigned short* __restrict__ wo,
                                                const float* __restrict__ sim,
                                                const float* __restrict__ beta,
                                                const unsigned short* __restrict__ wob,
                                                unsigned short* __restrict__ M,
                                                float* __restrict__ gamma, int b0) {
    int bid = blockIdx.x, tid = threadIdx.x;
    int b = b0 + (bid >> 8), o = bid & 255;
    __shared__ float lw[256];
    __shared__ float ls[8192];
    lw[tid] = bf2f(wo[o * 256 + tid]);
#pragma unroll
    for (int i = 0; i < 32; i++) ls[tid + i * 256] = sim[(size_t)b * 8192 + tid + i * 256];
    __syncthreads();
    int h = tid >> 5, d = tid & 31;
    float a = 0.f;
#pragma unroll
    for (int e = 0; e < 32; e++) {
        int ee = (e + d) & 31;
        a += lw[h * 32 + ee] * ls[h * 1024 + d * 32 + ee];
    }
    unsigned short mh = f2bf(a);
    M[((size_t)b * 256 + o) * 256 + tid] = mh;
    float g = bf2f(mh) * beta[b * 768 + tid];
#pragma unroll
    for (int off = 32; off > 0; off >>= 1) g += __shfl_xor(g, off);
    __shared__ float rg[4];
    if ((tid & 63) == 0) rg[tid >> 6] = g;
    __syncthreads();
    if (tid == 0) gamma[b * 256 + o] = rg[0] + rg[1] + rg[2] + rg[3] + bf2f(wob[o]);
}

// G2[b][o][0:256] = hi(M.Wq), G2[b][o][256:512] = lo  (row stride 512)
__global__ __launch_bounds__(256) void k_buildG(const unsigned short* __restrict__ M,
                                                const unsigned short* __restrict__ wqT,
                                                unsigned short* __restrict__ G2, int b0) {
    __shared__ __align__(16) unsigned short ldsbuf[4 * 8192];
    int tid = threadIdx.x, bid = blockIdx.x;
    int b = b0 + (bid >> 2), t = bid & 3;
    int o0 = (t >> 1) * 128, c0 = (t & 1) * 128;
    const unsigned short* A = M + (size_t)b * 65536 + (size_t)o0 * 256;   // rows o
    const unsigned short* B = wqT + (size_t)c0 * 256;                     // rows c
    f32x4 acc[4][4] = {};
    gemm_core_db<4, 3>(A, 256, B, 256, ldsbuf, tid, acc);

    int lane = tid & 63, l15 = lane & 15, quad = lane >> 4;
    int wave = tid >> 6, wm = wave & 1, wn = wave >> 1;
#pragma unroll
    for (int mi = 0; mi < 4; mi++) {
        int o_l = o0 + wm * 64 + mi * 16 + quad * 4;
#pragma unroll
        for (int ni = 0; ni < 4; ni++) {
            int c_l = c0 + wn * 64 + ni * 16 + l15;
            f32x4 v = acc[mi][ni];
#pragma unroll
            for (int r = 0; r < 4; r++) {
                float g = v[r];
                unsigned short hi = f2bf(g);
                unsigned short lo = f2bf(g - bf2f(hi));
                size_t rb = (size_t)b * 131072 + (size_t)(o_l + r) * 512 + c_l;
                G2[rb] = hi;
                G2[rb + 256] = lo;
            }
        }
    }
}

// GEMM2 (all batches): out[b][o][n] = xt[n][.] . G2[o][.] + gamma + x  (K=512).
// Multi-tile persistent: 4 n-tiles/block, grid 512 = 2 blocks/CU resident.
__global__ __launch_bounds__(256) void k_gemm2(const unsigned short* __restrict__ xt,
                                               const unsigned short* __restrict__ G2,
                                               const float* __restrict__ gamma,
                                               const void* __restrict__ xr,
                                               const int* __restrict__ flagp,
                                               void* __restrict__ outv) {
    __shared__ __align__(16) unsigned short lds[4 * 8192];   // 64 KB
    int tid = threadIdx.x, bid = blockIdx.x;
    int cpx = (int)gridDim.x >> 3;
    int L = (bid & 7) * cpx + (bid >> 3);
    int oblk = L & 1;                    // 2 oblks sharing xt adjacent on XCD
    int ngrp = (L >> 1) & 63;            // 64 groups of 4 n-tiles
    int b = L >> 7;
    int o0 = oblk * 128;
    const unsigned short* Ab = xt + ((size_t)b * 32768 + (size_t)ngrp * 512) * 256;
    const unsigned short* Bg = G2 + (size_t)b * 131072 + (size_t)o0 * 512;
    int lane = tid & 63, l15 = lane & 15, quad = lane >> 4;
    int wave = tid >> 6, wm = wave & 1, wn = wave >> 1;
    int f = *flagp;

    stage_tile(Ab, 256, lds, tid);
    stage_tile(Bg, 512, lds + 8192, tid);
    __syncthreads();
    for (int t = 0; t < 4; ++t) {
        f32x4 acc[4][4] = {};
#pragma unroll
        for (int kt = 0; kt < 8; ++kt) {
            int g = t * 8 + kt;
            unsigned short* cur = lds + (g & 1) * 16384;
            unsigned short* nxt = lds + ((g + 1) & 1) * 16384;
            if (g + 1 < 32) {
                int g2 = g + 1, t2 = g2 >> 3, k2 = g2 & 7;
                stage_tile(Ab + ((size_t)t2 * 128) * 256 + (k2 & 3) * 64, 256, nxt, tid);
                stage_tile(Bg + k2 * 64, 512, nxt + 8192, tid);
            }
            mfma_tile(cur, cur + 8192, l15, quad, wm, wn, acc);
            __syncthreads();
        }
        // Epilogue tile t (scratch = region 1; next tile's data in region 0).
        float* ldsF = (float*)(lds + 16384);
        size_t n0 = ((size_t)ngrp * 4 + t) * 128;
        for (int half = 0; half < 2; half++) {
            if (wn == half) {
#pragma unroll
                for (int mi = 0; mi < 4; mi++) {
#pragma unroll
                    for (int ni = 0; ni < 4; ni++) {
                        int o_h = ni * 16 + l15;
                        f32x4 v = acc[mi][ni];
#pragma unroll
                        for (int r = 0; r < 4; r++) {
                            int n_l = wm * 64 + mi * 16 + quad * 4 + r;
                            ldsF[(o_h * 128 + n_l) ^ ((o_h & 15) << 2)] = v[r];
                        }
                    }
                }
            }
            __syncthreads();
#pragma unroll
            for (int p = 0; p < 8; p++) {
                int o_h = p * 8 + (tid >> 5);
                int ch = tid & 31;
                float4 v = *(const float4*)&ldsF[(o_h * 128 + ch * 4) ^ ((o_h & 15) << 2)];
                int o = o0 + half * 64 + o_h;
                float bias = gamma[b * 256 + o];
                size_t base = ((size_t)b * 256 + o) * 32768 + n0 + ch * 4;
                if (f) {
                    float4 xv = *(const float4*)((const float*)xr + base);
                    float4 ov = make_float4(v.x + bias + xv.x, v.y + bias + xv.y,
                                            v.z + bias + xv.z, v.w + bias + xv.w);
                    *(float4*)((float*)outv + base) = ov;
                } else {
                    uint2 xr2 = *(const uint2*)((const unsigned short*)xr + base);
                    unsigned short xs[4] = {(unsigned short)(xr2.x & 0xffff), (unsigned short)(xr2.x >> 16),
                                            (unsigned short)(xr2.y & 0xffff), (unsigned short)(xr2.y >> 16)};
                    uint2 pv;
                    pv.x = pack2(f2bf(v.x + bias + bf2f(xs[0])), f2bf(v.y + bias + bf2f(xs[1])));
                    pv.y = pack2(f2bf(v.z + bias + bf2f(xs[2])), f2bf(v.w + bias + bf2f(xs[3])));
                    *(uint2*)((unsigned short*)outv + base) = pv;
                }
            }
            __syncthreads();   // also protects scratch before next stage
        }
    }
}

extern "C" void kernel_launch(void* const* d_in, const int* in_sizes, int n_in,
                              void* d_out, int out_size, void* d_ws, size_t ws_size,
                              hipStream_t stream) {
    const void* x    = d_in[0];
    const void* gnw  = d_in[1];
    const void* gnb  = d_in[2];
    const void* qkvw = d_in[3];
    const void* outw = d_in[4];
    const void* outb = d_in[5];
    char* ws = (char*)d_ws;

    // ---- workspace layout
    unsigned short* xt   = (unsigned short*)(ws);              // 64 MiB, [b][n][c]
    unsigned short* wdst = (unsigned short*)(ws + 67108864);   // 656896 B
    char* sm = ws + 68157440;
    int*    flag    = (int*)(sm);
    float2* gstats  = (float2*)(sm + 64);
    float*  beta    = (float*)(sm + 1024);      // 4*768 f32
    float2* stats   = (float2*)(sm + 16384);    // nb*256 f2 (pass-local)
    float*  gamma   = (float*)(sm + 24576);     // 4*256 f32
    float2* gn_part = (float2*)(sm + 32768);    // 2048 f2
    float*  sim     = (float*)(sm + 65536);     // 4*8*1024 f32
    unsigned short* M  = (unsigned short*)(sm + 262144);  // 4*256*256 bf16
    unsigned short* G2 = (unsigned short*)(sm + 786432);  // 4*256*512 bf16
    const size_t kv_off = 70254592;

    const unsigned short* wq   = wdst;
    const unsigned short* wo   = wdst + 196608;
    const unsigned short* wgnw = wdst + 262144;
    const unsigned short* wgnb = wdst + 262400;
    const unsigned short* wob  = wdst + 262656;
    const unsigned short* wqT  = wdst + 262912;

    int nb = 1;
    if      (ws_size >= kv_off + 4ull * (33554432 + 2097152)) nb = 4;
    else if (ws_size >= kv_off + 2ull * (33554432 + 2097152)) nb = 2;

    unsigned short* kv = (unsigned short*)(ws + kv_off);
    float* partials    = (float*)(ws + kv_off + (size_t)nb * 33554432);

    k_detect <<<dim3(1),    dim3(64),  0, stream>>>((const unsigned int*)x, flag);
    k_cvt_w  <<<dim3(1283), dim3(256), 0, stream>>>(qkvw, outw, gnw, gnb, outb, flag, wdst);
    k_gnsum  <<<dim3(2048), dim3(256), 0, stream>>>(x, flag, gn_part);
    k_gnfinal<<<dim3(16),   dim3(128), 0, stream>>>(gn_part, gstats);
    k_beta   <<<dim3(3072), dim3(64),  0, stream>>>(wq, wgnw, wgnb, gstats, beta);
    k_cvt_t  <<<dim3(8192), dim3(256), 0, stream>>>(x, flag, wgnw, gstats, xt);

    for (int pass = 0; pass < 4; pass += nb) {
        k_gemm1  <<<dim3(512 * nb), dim3(256), 0, stream>>>(wq, xt, beta, kv, pass);
        k_stats  <<<dim3(256 * nb), dim3(256), 0, stream>>>(kv, stats);
        k_sim    <<<dim3(128 * nb), dim3(256), 0, stream>>>(kv, stats, partials);
        k_combine<<<dim3(8 * nb),   dim3(256), 0, stream>>>(partials, sim, pass);
        k_buildM <<<dim3(256 * nb), dim3(256), 0, stream>>>(wo, sim, beta, wob, M, gamma, pass);
        k_buildG <<<dim3(4 * nb),   dim3(256), 0, stream>>>(M, wqT, G2, pass);
    }
    // GEMM2 for all batches in one launch (xt/G2/gamma persistent).
    k_gemm2<<<dim3(512), dim3(256), 0, stream>>>(xt, G2, gamma, x, flag, d_out);
}